// Round 15
// baseline (668.565 us; speedup 1.0000x reference)
//
#include <hip/hip_runtime.h>

constexpr int N_NODES = 100000;
constexpr int F_IN    = 32;
constexpr int H       = 128;
constexpr int OUT_F   = 200;
constexpr int NEDGES  = 1600000;
constexpr float EPS   = 1e-5f;

constexpr int HIST8_BLKS = (NEDGES / 8 + 255) / 256;  // 782
constexpr int WS_BLKS    = 80;                        // 5*128*128/1024
constexpr int NPARTS     = (N_NODES + 255) / 256;     // 391
constexpr int FILL_BLKS  = (NEDGES / 4 + 255) / 256;  // 1563
constexpr int TILE_BLKS  = (N_NODES + 63) / 64;       // 1563
constexpr int PRE3_BLKS  = HIST8_BLKS + TILE_BLKS;    // 2345 (1:2 interleave)
constexpr int MM_BLKS    = TILE_BLKS * 2;             // 3126 (64r x 64c tiles)

typedef __attribute__((ext_vector_type(8))) short  short8;
typedef __attribute__((ext_vector_type(4))) float  f32x4;
typedef __attribute__((ext_vector_type(2))) float  fv2;

__device__ __forceinline__ void fma4(float4& a, float s, const float4& w) {
  a.x = fmaf(s, w.x, a.x); a.y = fmaf(s, w.y, a.y);
  a.z = fmaf(s, w.z, a.z); a.w = fmaf(s, w.w, a.w);
}

__device__ __forceinline__ unsigned short f2bf(float f) {  // RNE
  union { float f; unsigned u; } v; v.f = f;
  unsigned r = v.u + 0x7fffu + ((v.u >> 16) & 1u);
  return (unsigned short)(r >> 16);
}
__device__ __forceinline__ float bf2f(unsigned short s) {
  union { unsigned u; float f; } v; v.u = ((unsigned)s) << 16;
  return v.f;
}
__device__ __forceinline__ float bflo(unsigned u) { return __uint_as_float(u << 16); }
__device__ __forceinline__ float bfhi(unsigned u) { return __uint_as_float(u & 0xffff0000u); }
__device__ __forceinline__ unsigned pack2(float lo, float hi) {
  return (unsigned)f2bf(lo) | ((unsigned)f2bf(hi) << 16);
}
__device__ __forceinline__ void st_bf4(unsigned short* p, float4 v) {
  uint2 o; o.x = pack2(v.x, v.y); o.y = pack2(v.z, v.w);
  *(uint2*)p = o;
}

// ---------------- fp8 e4m3fn helpers ----------------
#if __has_builtin(__builtin_amdgcn_cvt_pk_f32_fp8) && __has_builtin(__builtin_amdgcn_cvt_pk_fp8_f32)
#define HAVE_FP8_CVT 1
#endif

#ifndef HAVE_FP8_CVT
__device__ __forceinline__ float fp8_dec1(unsigned b) {
  unsigned s = (b >> 7) & 1u, E = (b >> 3) & 15u, m = b & 7u;
  float v;
  if (E) {
    union { unsigned u; float f; } t;
    t.u = (s << 31) | ((E + 120u) << 23) | (m << 20);
    v = t.f;
  } else {
    v = (s ? -1.f : 1.f) * (float)m * 0.001953125f;
  }
  return v;
}
#endif

template <bool HI>
__device__ __forceinline__ fv2 fp8x2(unsigned u) {
#ifdef HAVE_FP8_CVT
  return __builtin_amdgcn_cvt_pk_f32_fp8((int)u, HI);
#else
  unsigned p = HI ? (u >> 16) : u;
  fv2 r; r.x = fp8_dec1(p & 0xffu); r.y = fp8_dec1((p >> 8) & 0xffu);
  return r;
#endif
}

__device__ __forceinline__ unsigned char f32_to_fp8(float f) {
#ifdef HAVE_FP8_CVT
  return (unsigned char)(__builtin_amdgcn_cvt_pk_fp8_f32(f, f, 0, false) & 0xff);
#else
  union { float f; unsigned u; } t; t.f = f;
  unsigned s = t.u >> 31;
  float a = fabsf(f);
  if (a > 448.f) a = 448.f;
  t.f = a;
  int e = (int)((t.u >> 23) & 0xff) - 127;
  unsigned char r;
  if (a == 0.f) {
    r = 0;
  } else if (e >= -6) {
    unsigned m = t.u & 0x7fffffu;
    unsigned keep = m >> 20, rest = m & 0xfffffu;
    keep += (rest > 0x80000u) || (rest == 0x80000u && (keep & 1u));
    int E = e + 7;
    if (keep == 8u) { keep = 0u; E += 1; }
    if (E >= 16) { E = 15; keep = 6u; }
    r = (unsigned char)((E << 3) | keep);
  } else {
    int mi = (int)(a * 512.f + 0.5f);
    r = (mi > 7) ? (unsigned char)(1u << 3) : (unsigned char)mi;
  }
  return (unsigned char)(r | (s << 7));
#endif
}

// ---------------- k_ws: W -> bf16 transposed ----------------
__global__ void k_ws(const float* __restrict__ W_conv,
                     const float* __restrict__ W_res,
                     unsigned short* __restrict__ whiT) {
  int base = blockIdx.x * 1024;
#pragma unroll
  for (int j = 0; j < 4; ++j) {
    int idx = base + j * 256 + threadIdx.x;
    if (idx < 5 * H * H) {
      int m = idx >> 14, rr = idx & 16383;
      int k = rr >> 7, n = rr & 127;
      const float* src = (m < 4) ? (W_conv + m * H * H) : W_res;
      whiT[m * H * H + n * H + k] = f2bf(src[k * H + n]);
    }
  }
}

// mm from LDS tile: 64 rows x 128 cols, wave = 32r x 64c (B frags hoisted)
__device__ __forceinline__ void mm_lds_fp8(const unsigned short* sA,
                                           const unsigned short* __restrict__ WT,
                                           int n0, int t,
                                           unsigned char* __restrict__ htOut) {
  int wave = t >> 6, lane = t & 63;
  int wr = wave >> 1, wc = wave & 1;
  int m = lane & 15, quad = (lane >> 4) & 3;
  short8 bh[4][4];
#pragma unroll
  for (int q = 0; q < 4; ++q)
#pragma unroll
    for (int ct = 0; ct < 4; ++ct) {
      int n = wc * 64 + ct * 16 + m;
      bh[q][ct] = *(const short8*)(WT + n * H + q * 32 + quad * 8);
    }
  f32x4 acc[2][4];
#pragma unroll
  for (int i = 0; i < 2; ++i)
#pragma unroll
    for (int j = 0; j < 4; ++j) acc[i][j] = (f32x4){0.f, 0.f, 0.f, 0.f};
#pragma unroll
  for (int q = 0; q < 4; ++q) {
    short8 ah[2];
#pragma unroll
    for (int rt = 0; rt < 2; ++rt)
      ah[rt] = *(const short8*)(sA + (wr * 32 + rt * 16 + m) * 136 + q * 32 + quad * 8);
#pragma unroll
    for (int rt = 0; rt < 2; ++rt)
#pragma unroll
      for (int ct = 0; ct < 4; ++ct)
        acc[rt][ct] = __builtin_amdgcn_mfma_f32_16x16x32_bf16(ah[rt], bh[q][ct], acc[rt][ct], 0, 0, 0);
  }
#pragma unroll
  for (int rt = 0; rt < 2; ++rt)
#pragma unroll
    for (int ct = 0; ct < 4; ++ct) {
      int col = wc * 64 + ct * 16 + m;
#pragma unroll
      for (int rr = 0; rr < 4; ++rr) {
        int gn = n0 + wr * 32 + rt * 16 + quad * 4 + rr;
        if (gn < N_NODES) htOut[(size_t)gn * H + col] = f32_to_fp8(acc[rt][ct][rr]);
      }
    }
}

// ---------------- k_pre3: hist | (embed 64-node tile -> LDS -> mm W0), 1:2 ----------------
__global__ __launch_bounds__(256) void k_pre3(
    const int* __restrict__ ei, int* __restrict__ deg,
    unsigned char* __restrict__ ranks,
    const float* __restrict__ x, const float* __restrict__ W_emb,
    const float* __restrict__ b_emb, unsigned short* __restrict__ h,
    const unsigned short* __restrict__ W0T, unsigned char* __restrict__ ht8) {
  __shared__ __align__(16) char smem[25600];
  int t = threadIdx.x;
  int id = blockIdx.x;
  int q3 = id / 3, r3 = id - q3 * 3;
  if (r3 == 0) {
    int i = q3 * 256 + t;
    if (i < NEDGES / 8) {
      int4 a = *(const int4*)(ei + NEDGES + 8 * i);
      int4 b = *(const int4*)(ei + NEDGES + 8 * i + 4);
      union { unsigned char c[8]; uint2 u; } rr;
      rr.c[0] = (unsigned char)atomicAdd(&deg[a.x], 1);
      rr.c[1] = (unsigned char)atomicAdd(&deg[a.y], 1);
      rr.c[2] = (unsigned char)atomicAdd(&deg[a.z], 1);
      rr.c[3] = (unsigned char)atomicAdd(&deg[a.w], 1);
      rr.c[4] = (unsigned char)atomicAdd(&deg[b.x], 1);
      rr.c[5] = (unsigned char)atomicAdd(&deg[b.y], 1);
      rr.c[6] = (unsigned char)atomicAdd(&deg[b.z], 1);
      rr.c[7] = (unsigned char)atomicAdd(&deg[b.w], 1);
      ((uint2*)ranks)[i] = rr.u;
    }
  } else {
    int j = q3 * 2 + (r3 - 1);
    int n0 = j * 64;
    float* sW = (float*)smem;
    float* sX = sW + 4096;
    unsigned short* sH = (unsigned short*)smem;
#pragma unroll
    for (int p = 0; p < 4; ++p)
      ((float4*)sW)[t + p * 256] = ((const float4*)W_emb)[t + p * 256];
#pragma unroll
    for (int p = 0; p < 2; ++p) {
      int fi = t * 2 + p;
      int row = fi >> 3, k4 = (fi & 7) * 4;
      int gn = n0 + row; if (gn >= N_NODES) gn = N_NODES - 1;
      *(float4*)(sX + row * 36 + k4) = *(const float4*)(x + (size_t)gn * F_IN + k4);
    }
    __syncthreads();
    // conflict-free sW reads: col0 = (t&3)*4 -> banks {0,4,8,12}(+16i)
    int nr = t >> 2, col0 = (t & 3) * 4;
    float4 acc[8];
#pragma unroll
    for (int i = 0; i < 8; ++i) acc[i] = make_float4(0.f, 0.f, 0.f, 0.f);
#pragma unroll 4
    for (int k = 0; k < F_IN; ++k) {
      float xv = sX[nr * 36 + k];
      const float* wp = sW + k * H + col0;
#pragma unroll
      for (int i = 0; i < 8; ++i) fma4(acc[i], xv, *(const float4*)(wp + i * 16));
    }
#pragma unroll
    for (int i = 0; i < 8; ++i) {
      float4 bv = *(const float4*)(b_emb + col0 + i * 16);
      acc[i].x += bv.x; acc[i].y += bv.y; acc[i].z += bv.z; acc[i].w += bv.w;
    }
    __syncthreads();  // done reading sW/sX; reuse as sH
    int node = n0 + nr;
    unsigned short* hr = h + (size_t)node * H + col0;
#pragma unroll
    for (int i = 0; i < 8; ++i) {
      st_bf4(sH + nr * 136 + col0 + i * 16, acc[i]);
      if (node < N_NODES) st_bf4(hr + i * 16, acc[i]);
    }
    __syncthreads();
    mm_lds_fp8(sH, W0T, n0, t, ht8);
  }
}

// ---------------- scans ----------------
__global__ void k_scan_a(const int* __restrict__ deg, int* __restrict__ offs,
                         int* __restrict__ parts, float* __restrict__ dinv) {
  __shared__ int s[256];
  int i = blockIdx.x * 256 + threadIdx.x;
  int d = (i < N_NODES) ? deg[i] : 0;
  s[threadIdx.x] = d;
  __syncthreads();
#pragma unroll
  for (int off = 1; off < 256; off <<= 1) {
    int v = (threadIdx.x >= off) ? s[threadIdx.x - off] : 0;
    __syncthreads();
    s[threadIdx.x] += v;
    __syncthreads();
  }
  if (i < N_NODES) {
    offs[i] = s[threadIdx.x] - d;   // block-local exclusive
    dinv[i] = rsqrtf((float)(d + 1));
  }
  if (threadIdx.x == 255) parts[blockIdx.x] = s[255];
}

__global__ void k_scan_b(int* __restrict__ parts, int nparts) {
  __shared__ int s[512];
  int t = threadIdx.x;
  int d = (t < nparts) ? parts[t] : 0;
  s[t] = d;
  __syncthreads();
#pragma unroll
  for (int off = 1; off < 512; off <<= 1) {
    int v = (t >= off) ? s[t - off] : 0;
    __syncthreads();
    s[t] += v;
    __syncthreads();
  }
  if (t < nparts) parts[t] = s[t] - d;
}

// ---------------- k_fill ----------------
__global__ __launch_bounds__(256) void k_fill(
    const int* __restrict__ ei, const unsigned char* __restrict__ ranks,
    const int* __restrict__ offs, const int* __restrict__ parts,
    const float* __restrict__ dinv, unsigned* __restrict__ csr) {
  int i = blockIdx.x * 256 + threadIdx.x;
  if (i < NEDGES / 4) {
    int4 s4 = *(const int4*)(ei + 4 * i);
    int4 d4 = *(const int4*)(ei + NEDGES + 4 * i);
    uchar4 r4 = ((const uchar4*)ranks)[i];
    int p0 = offs[d4.x] + parts[d4.x >> 8] + r4.x;
    int p1 = offs[d4.y] + parts[d4.y >> 8] + r4.y;
    int p2 = offs[d4.z] + parts[d4.z >> 8] + r4.z;
    int p3 = offs[d4.w] + parts[d4.w >> 8] + r4.w;
    csr[p0] = ((unsigned)s4.x << 15) | (unsigned)(dinv[s4.x] * 32767.f + 0.5f);
    csr[p1] = ((unsigned)s4.y << 15) | (unsigned)(dinv[s4.y] * 32767.f + 0.5f);
    csr[p2] = ((unsigned)s4.z << 15) | (unsigned)(dinv[s4.z] * 32767.f + 0.5f);
    csr[p3] = ((unsigned)s4.w << 15) | (unsigned)(dinv[s4.w] * 32767.f + 0.5f);
  }
}

// ---------------- mm core for layers 1-3 (global A) ----------------
struct MMAcc { f32x4 a[2][2]; };

__device__ __forceinline__ MMAcc mm_core(const unsigned short* __restrict__ A,
                                         const unsigned short* __restrict__ WhiT,
                                         int n0, int c0, int t,
                                         unsigned short* sA) {
  int wave = t >> 6, lane = t & 63;
  int wr = wave >> 1, wc = wave & 1;
  int m = lane & 15, quad = (lane >> 4) & 3;
  short8 bh[4][2];
#pragma unroll
  for (int q = 0; q < 4; ++q)
#pragma unroll
    for (int ct = 0; ct < 2; ++ct) {
      int n = c0 + wc * 32 + ct * 16 + m;
      bh[q][ct] = *(const short8*)(WhiT + n * H + q * 32 + quad * 8);
    }
#pragma unroll
  for (int p = 0; p < 4; ++p) {
    int fi = t + p * 256;
    int row = fi >> 4, c8 = (fi & 15) * 8;
    int gn = n0 + row; if (gn >= N_NODES) gn = N_NODES - 1;
    *(uint4*)(sA + row * 136 + c8) = *(const uint4*)(A + (size_t)gn * H + c8);
  }
  __syncthreads();
  MMAcc r;
#pragma unroll
  for (int i = 0; i < 2; ++i)
#pragma unroll
    for (int j = 0; j < 2; ++j) r.a[i][j] = (f32x4){0.f, 0.f, 0.f, 0.f};
#pragma unroll
  for (int q = 0; q < 4; ++q) {
    short8 ah[2];
#pragma unroll
    for (int rt = 0; rt < 2; ++rt)
      ah[rt] = *(const short8*)(sA + (wr * 32 + rt * 16 + m) * 136 + q * 32 + quad * 8);
#pragma unroll
    for (int rt = 0; rt < 2; ++rt)
#pragma unroll
      for (int ct = 0; ct < 2; ++ct)
        r.a[rt][ct] = __builtin_amdgcn_mfma_f32_16x16x32_bf16(ah[rt], bh[q][ct], r.a[rt][ct], 0, 0, 0);
  }
  return r;
}

__device__ __forceinline__ void mm_store_fp8(const MMAcc& r, unsigned char* ht8,
                                             int n0, int c0, int t) {
  int wave = t >> 6, lane = t & 63;
  int wr = wave >> 1, wc = wave & 1;
  int m = lane & 15, quad = (lane >> 4) & 3;
#pragma unroll
  for (int rt = 0; rt < 2; ++rt)
#pragma unroll
    for (int ct = 0; ct < 2; ++ct) {
      int col = c0 + wc * 32 + ct * 16 + m;
#pragma unroll
      for (int rr = 0; rr < 4; ++rr) {
        int gn = n0 + wr * 32 + rt * 16 + quad * 4 + rr;
        if (gn < N_NODES) ht8[(size_t)gn * H + col] = f32_to_fp8(r.a[rt][ct][rr]);
      }
    }
}

__global__ __launch_bounds__(256) void k_mm(const unsigned short* __restrict__ A,
                                            const unsigned short* __restrict__ WhiT,
                                            unsigned char* __restrict__ ht8) {
  __shared__ __align__(16) unsigned short sA[64 * 136];
  int j = blockIdx.x;
  int n0 = (j >> 1) * 64, c0 = (j & 1) * 64;
  MMAcc r = mm_core(A, WhiT, n0, c0, threadIdx.x, sA);
  mm_store_fp8(r, ht8, n0, c0, threadIdx.x);
}

// layer-2 dual GEMM
__global__ __launch_bounds__(256) void k_mmd(const unsigned short* __restrict__ A,
    const unsigned short* __restrict__ WcT, const unsigned short* __restrict__ WrT,
    const float* __restrict__ bias,
    unsigned char* __restrict__ ht8, unsigned short* __restrict__ resb) {
  __shared__ __align__(16) unsigned short sA[64 * 136];
  int t = threadIdx.x;
  int j = blockIdx.x;
  int n0 = (j >> 1) * 64, c0 = (j & 1) * 64;
  int wave = t >> 6, lane = t & 63;
  int wr = wave >> 1, wc = wave & 1;
  int m = lane & 15, quad = (lane >> 4) & 3;
  short8 bhc[4][2], bhr[4][2];
#pragma unroll
  for (int q = 0; q < 4; ++q)
#pragma unroll
    for (int ct = 0; ct < 2; ++ct) {
      int n = c0 + wc * 32 + ct * 16 + m;
      bhc[q][ct] = *(const short8*)(WcT + n * H + q * 32 + quad * 8);
      bhr[q][ct] = *(const short8*)(WrT + n * H + q * 32 + quad * 8);
    }
#pragma unroll
  for (int p = 0; p < 4; ++p) {
    int fi = t + p * 256;
    int row = fi >> 4, c8 = (fi & 15) * 8;
    int gn = n0 + row; if (gn >= N_NODES) gn = N_NODES - 1;
    *(uint4*)(sA + row * 136 + c8) = *(const uint4*)(A + (size_t)gn * H + c8);
  }
  __syncthreads();
  f32x4 accC[2][2], accR[2][2];
#pragma unroll
  for (int i = 0; i < 2; ++i)
#pragma unroll
    for (int jj = 0; jj < 2; ++jj) {
      accC[i][jj] = (f32x4){0.f, 0.f, 0.f, 0.f};
      accR[i][jj] = (f32x4){0.f, 0.f, 0.f, 0.f};
    }
#pragma unroll
  for (int q = 0; q < 4; ++q) {
    short8 ah[2];
#pragma unroll
    for (int rt = 0; rt < 2; ++rt)
      ah[rt] = *(const short8*)(sA + (wr * 32 + rt * 16 + m) * 136 + q * 32 + quad * 8);
#pragma unroll
    for (int rt = 0; rt < 2; ++rt)
#pragma unroll
      for (int ct = 0; ct < 2; ++ct) {
        accC[rt][ct] = __builtin_amdgcn_mfma_f32_16x16x32_bf16(ah[rt], bhc[q][ct], accC[rt][ct], 0, 0, 0);
        accR[rt][ct] = __builtin_amdgcn_mfma_f32_16x16x32_bf16(ah[rt], bhr[q][ct], accR[rt][ct], 0, 0, 0);
      }
  }
#pragma unroll
  for (int rt = 0; rt < 2; ++rt)
#pragma unroll
    for (int ct = 0; ct < 2; ++ct) {
      int col = c0 + wc * 32 + ct * 16 + m;
      float bv = bias[col];
#pragma unroll
      for (int rr = 0; rr < 4; ++rr) {
        int gn = n0 + wr * 32 + rt * 16 + quad * 4 + rr;
        if (gn < N_NODES) {
          ht8[(size_t)gn * H + col]  = f32_to_fp8(accC[rt][ct][rr]);
          resb[(size_t)gn * H + col] = f2bf(accR[rt][ct][rr] + bv);
        }
      }
    }
}

// ---------------- aggregate(fp8 ht) + bias + LN + relu + residual(bf16) ----------------
// 8 groups x 8 lanes: lane owns 16 feats -> one uint4 (16 B) per edge-row
// gather (halves TA requests vs r14's uint2 pairs); 16-edge batches keep
// 16 loads in flight per wave. OOB lanes gather row 0 (L1-hot, w=0).
__global__ __launch_bounds__(256) void k_agg(
    const unsigned char* __restrict__ ht8, const unsigned short* __restrict__ res,
    const float* __restrict__ dinv, const int* __restrict__ offs,
    const int* __restrict__ parts, const int* __restrict__ deg,
    const unsigned* __restrict__ csr,
    const float* __restrict__ bias, const float* __restrict__ lng,
    const float* __restrict__ lnb, unsigned short* __restrict__ hout) {
  int wid = threadIdx.x >> 6, lane = threadIdx.x & 63;
  int node = blockIdx.x * 4 + wid;
  if (node >= N_NODES) return;
  int grp = lane >> 3, fl = lane & 7;   // 8 groups x 8 feature-lanes
  int start = offs[node] + parts[node >> 8], cnt = deg[node];
  float di = dinv[node];
  const unsigned char* hb = ht8 + fl * 16;
  float acc[16];
  {
    uint4 u = *(const uint4*)(hb + (size_t)node * 128);
    float sw = (grp == 0) ? di * di : 0.f;  // self-loop counted once
    fv2 a0 = fp8x2<false>(u.x), a1 = fp8x2<true>(u.x);
    fv2 a2 = fp8x2<false>(u.y), a3 = fp8x2<true>(u.y);
    fv2 a4 = fp8x2<false>(u.z), a5 = fp8x2<true>(u.z);
    fv2 a6 = fp8x2<false>(u.w), a7 = fp8x2<true>(u.w);
    acc[0]  = sw * a0.x; acc[1]  = sw * a0.y; acc[2]  = sw * a1.x; acc[3]  = sw * a1.y;
    acc[4]  = sw * a2.x; acc[5]  = sw * a2.y; acc[6]  = sw * a3.x; acc[7]  = sw * a3.y;
    acc[8]  = sw * a4.x; acc[9]  = sw * a4.y; acc[10] = sw * a5.x; acc[11] = sw * a5.y;
    acc[12] = sw * a6.x; acc[13] = sw * a6.y; acc[14] = sw * a7.x; acc[15] = sw * a7.y;
  }
  float ddq = di * (1.f / 32767.f);
  for (int b0 = 0; b0 < cnt; b0 += 64) {
    int mm_ = min(64, cnt - b0);
    int s = 0; float w = 0.f;
    if (lane < mm_) {
      unsigned ev = csr[start + b0 + lane];
      s = (int)(ev >> 15);
      w = (float)(ev & 32767u) * ddq;
    }
    for (int e0 = 0; e0 < mm_; e0 += 16) {
      uint4 uu[2]; float ww[2];
#pragma unroll
      for (int jj = 0; jj < 2; ++jj) {
        int idx = e0 + jj * 8 + grp;   // <= 48+8+7 = 63 always
        int ss = __shfl(s, idx, 64);
        ww[jj] = __shfl(w, idx, 64);
        uu[jj] = *(const uint4*)(hb + (size_t)ss * 128);
      }
#pragma unroll
      for (int jj = 0; jj < 2; ++jj) {
        float we = ww[jj];
        fv2 a0 = fp8x2<false>(uu[jj].x), a1 = fp8x2<true>(uu[jj].x);
        fv2 a2 = fp8x2<false>(uu[jj].y), a3 = fp8x2<true>(uu[jj].y);
        fv2 a4 = fp8x2<false>(uu[jj].z), a5 = fp8x2<true>(uu[jj].z);
        fv2 a6 = fp8x2<false>(uu[jj].w), a7 = fp8x2<true>(uu[jj].w);
        acc[0]  = fmaf(we, a0.x, acc[0]);  acc[1]  = fmaf(we, a0.y, acc[1]);
        acc[2]  = fmaf(we, a1.x, acc[2]);  acc[3]  = fmaf(we, a1.y, acc[3]);
        acc[4]  = fmaf(we, a2.x, acc[4]);  acc[5]  = fmaf(we, a2.y, acc[5]);
        acc[6]  = fmaf(we, a3.x, acc[6]);  acc[7]  = fmaf(we, a3.y, acc[7]);
        acc[8]  = fmaf(we, a4.x, acc[8]);  acc[9]  = fmaf(we, a4.y, acc[9]);
        acc[10] = fmaf(we, a5.x, acc[10]); acc[11] = fmaf(we, a5.y, acc[11]);
        acc[12] = fmaf(we, a6.x, acc[12]); acc[13] = fmaf(we, a6.y, acc[13]);
        acc[14] = fmaf(we, a7.x, acc[14]); acc[15] = fmaf(we, a7.y, acc[15]);
      }
    }
  }
  // merge the 8 groups (lanes with equal fl hold the same feature slice)
#pragma unroll
  for (int j = 0; j < 16; ++j) {
    acc[j] += __shfl_xor(acc[j], 8, 64);
    acc[j] += __shfl_xor(acc[j], 16, 64);
    acc[j] += __shfl_xor(acc[j], 32, 64);
  }
#pragma unroll
  for (int i = 0; i < 4; ++i) {
    float4 bv = *(const float4*)(bias + fl * 16 + i * 4);
    acc[i * 4 + 0] += bv.x; acc[i * 4 + 1] += bv.y;
    acc[i * 4 + 2] += bv.z; acc[i * 4 + 3] += bv.w;
  }
  float sl = 0.f;
#pragma unroll
  for (int j = 0; j < 16; ++j) sl += acc[j];
#pragma unroll
  for (int mk = 1; mk <= 4; mk <<= 1) sl += __shfl_xor(sl, mk, 64);
  float mu = sl * (1.f / 128.f);
  float d[16];
  float vl = 0.f;
#pragma unroll
  for (int j = 0; j < 16; ++j) { d[j] = acc[j] - mu; vl = fmaf(d[j], d[j], vl); }
#pragma unroll
  for (int mk = 1; mk <= 4; mk <<= 1) vl += __shfl_xor(vl, mk, 64);
  float rs = rsqrtf(vl * (1.f / 128.f) + EPS);
  if (grp == 0) {
    const unsigned short* rp = res + (size_t)node * 128 + fl * 16;
    unsigned short* op = hout + (size_t)node * 128 + fl * 16;
#pragma unroll
    for (int half = 0; half < 2; ++half) {
      uint4 rv = *(const uint4*)(rp + half * 8);
      float rvf[8] = {bflo(rv.x), bfhi(rv.x), bflo(rv.y), bfhi(rv.y),
                      bflo(rv.z), bfhi(rv.z), bflo(rv.w), bfhi(rv.w)};
      uint4 ov;
      unsigned* ovp = (unsigned*)&ov;
#pragma unroll
      for (int pp = 0; pp < 4; ++pp) {
        int j = half * 8 + pp * 2;
        int gi = fl * 16 + j;
        float o0 = fmaxf(fmaf(d[j] * rs, lng[gi], lnb[gi]), 0.f) + rvf[pp * 2];
        float o1 = fmaxf(fmaf(d[j + 1] * rs, lng[gi + 1], lnb[gi + 1]), 0.f) + rvf[pp * 2 + 1];
        ovp[pp] = pack2(o0, o1);
      }
      *(uint4*)(op + half * 8) = ov;
    }
  }
}

// ---------------- mean pool (bf16 h) ----------------
__global__ void k_pool(const unsigned short* __restrict__ h, float* __restrict__ pool) {
  int f = threadIdx.x;  // 128
  float acc = 0.f;
  for (int n = blockIdx.x; n < N_NODES; n += gridDim.x)
    acc += bf2f(h[(size_t)n * H + f]);
  atomicAdd(&pool[f], acc);
}

// ---------------- head ----------------
__global__ void k_head(const float* __restrict__ pool, const float* __restrict__ Wfc1,
                       const float* __restrict__ bfc1, const float* __restrict__ g,
                       const float* __restrict__ bb, const float* __restrict__ Wfc2,
                       const float* __restrict__ bfc2, float* __restrict__ out) {
  __shared__ float sm[128], s1[128], stats[2];
  int t = threadIdx.x;
  if (t < 128) sm[t] = pool[t] * (1.f / (float)N_NODES);
  __syncthreads();
  if (t < 128) {
    float a = bfc1[t];
    for (int k = 0; k < 128; ++k) a = fmaf(sm[k], Wfc1[k * 128 + t], a);
    s1[t] = a;
  }
  __syncthreads();
  if (t == 0) {
    float mu = 0.f;
    for (int k = 0; k < 128; ++k) mu += s1[k];
    mu *= (1.f / 128.f);
    float var = 0.f;
    for (int k = 0; k < 128; ++k) { float d = s1[k] - mu; var += d * d; }
    var *= (1.f / 128.f);
    stats[0] = mu; stats[1] = rsqrtf(var + EPS);
  }
  __syncthreads();
  if (t < 128) s1[t] = fmaxf((s1[t] - stats[0]) * stats[1] * g[t] + bb[t], 0.f);
  __syncthreads();
  if (t < OUT_F) {
    float a = bfc2[t];
    for (int k = 0; k < 128; ++k) a = fmaf(s1[k], Wfc2[k * OUT_F + t], a);
    out[t] = a;
  }
}

extern "C" void kernel_launch(void* const* d_in, const int* in_sizes, int n_in,
                              void* d_out, int out_size, void* d_ws, size_t ws_size,
                              hipStream_t stream) {
  const float* x      = (const float*)d_in[0];
  const int*   ei     = (const int*)d_in[1];
  const float* W_emb  = (const float*)d_in[2];
  const float* b_emb  = (const float*)d_in[3];
  const float* W_conv = (const float*)d_in[4];
  const float* b_conv = (const float*)d_in[5];
  const float* ln_g   = (const float*)d_in[6];
  const float* ln_b   = (const float*)d_in[7];
  const float* W_res  = (const float*)d_in[8];
  const float* b_res  = (const float*)d_in[9];
  const float* W_fc1  = (const float*)d_in[10];
  const float* b_fc1  = (const float*)d_in[11];
  const float* fcn_g  = (const float*)d_in[12];
  const float* fcn_b  = (const float*)d_in[13];
  const float* W_fc2  = (const float*)d_in[14];
  const float* b_fc2  = (const float*)d_in[15];
  float* out = (float*)d_out;

  char* p = (char*)d_ws;
  auto take = [&](size_t bytes) {
    char* r = p; p += (bytes + 255) & ~(size_t)255; return r;
  };
  unsigned short* bufA = (unsigned short*)take((size_t)N_NODES * H * 2);
  unsigned short* bufB = (unsigned short*)take((size_t)N_NODES * H * 2);
  unsigned short* bufC = (unsigned short*)take((size_t)N_NODES * H * 2);
  unsigned char*  ht8  = (unsigned char*)take((size_t)N_NODES * H);
  unsigned short* whiT = (unsigned short*)take((size_t)5 * H * H * 2);
  int*   deg  = (int*)take(N_NODES * 4);
  int*   offs = (int*)take(N_NODES * 4);
  int*   parts= (int*)take(512 * 4);
  float* dinv = (float*)take(N_NODES * 4);
  unsigned char* ranks = (unsigned char*)take(NEDGES);
  unsigned* csr = (unsigned*)take((size_t)NEDGES * 4);
  float* pool = (float*)take(128 * 4);

  (void)hipMemsetAsync(deg, 0, N_NODES * 4, stream);
  (void)hipMemsetAsync(pool, 0, 128 * 4, stream);

  k_ws<<<WS_BLKS, 256, 0, stream>>>(W_conv, W_res, whiT);
  k_pre3<<<PRE3_BLKS, 256, 0, stream>>>(ei, deg, ranks, x, W_emb, b_emb, bufA,
                                        whiT + 0 * H * H, ht8);
  k_scan_a<<<NPARTS, 256, 0, stream>>>(deg, offs, parts, dinv);
  k_scan_b<<<1, 512, 0, stream>>>(parts, NPARTS);
  k_fill<<<FILL_BLKS, 256, 0, stream>>>(ei, ranks, offs, parts, dinv, csr);

  int aggg = (N_NODES + 3) / 4;
  // L0: res=h0=A -> h1=C
  k_agg<<<aggg, 256, 0, stream>>>(ht8, bufA, dinv, offs, parts, deg, csr,
                                  b_conv + 0 * H, ln_g + 0 * H, ln_b + 0 * H, bufC);
  // L1: h1=C -> ht8 -> h2=A (res=C)
  k_mm<<<MM_BLKS, 256, 0, stream>>>(bufC, whiT + 1 * H * H, ht8);
  k_agg<<<aggg, 256, 0, stream>>>(ht8, bufC, dinv, offs, parts, deg, csr,
                                  b_conv + 1 * H, ln_g + 1 * H, ln_b + 1 * H, bufA);
  // L2: h2=A; dual: ht8=A@W2, B=bf16(A@Wres+bres); agg -> h3=C (res=B)
  k_mmd<<<MM_BLKS, 256, 0, stream>>>(bufA, whiT + 2 * H * H, whiT + 4 * H * H,
                                     b_res, ht8, bufB);
  k_agg<<<aggg, 256, 0, stream>>>(ht8, bufB, dinv, offs, parts, deg, csr,
                                  b_conv + 2 * H, ln_g + 2 * H, ln_b + 2 * H, bufC);
  // L3: h3=C -> ht8 -> h4=A (res=C)
  k_mm<<<MM_BLKS, 256, 0, stream>>>(bufC, whiT + 3 * H * H, ht8);
  k_agg<<<aggg, 256, 0, stream>>>(ht8, bufC, dinv, offs, parts, deg, csr,
                                  b_conv + 3 * H, ln_g + 3 * H, ln_b + 3 * H, bufA);

  k_pool<<<512, 128, 0, stream>>>(bufA, pool);
  k_head<<<1, 256, 0, stream>>>(pool, W_fc1, b_fc1, fcn_g, fcn_b,
                                W_fc2, b_fc2, out);
}

// Round 16
// 549.107 us; speedup vs baseline: 1.2175x; 1.2175x over previous
//
#include <hip/hip_runtime.h>

constexpr int N_NODES = 100000;
constexpr int F_IN    = 32;
constexpr int H       = 128;
constexpr int OUT_F   = 200;
constexpr int NEDGES  = 1600000;
constexpr float EPS   = 1e-5f;

constexpr int HIST8_BLKS = (NEDGES / 8 + 255) / 256;  // 782
constexpr int WS_BLKS    = 80;                        // 5*128*128/1024
constexpr int NPARTS     = (N_NODES + 255) / 256;     // 391
constexpr int FILL_BLKS  = (NEDGES / 4 + 255) / 256;  // 1563
constexpr int TILE_BLKS  = (N_NODES + 63) / 64;       // 1563
constexpr int PRE3_BLKS  = HIST8_BLKS + TILE_BLKS;    // 2345 (1:2 interleave)
constexpr int MM_BLKS    = TILE_BLKS * 2;             // 3126 (64r x 64c tiles)

typedef __attribute__((ext_vector_type(8))) short  short8;
typedef __attribute__((ext_vector_type(4))) float  f32x4;
typedef __attribute__((ext_vector_type(2))) float  fv2;

__device__ __forceinline__ void fma4(float4& a, float s, const float4& w) {
  a.x = fmaf(s, w.x, a.x); a.y = fmaf(s, w.y, a.y);
  a.z = fmaf(s, w.z, a.z); a.w = fmaf(s, w.w, a.w);
}

__device__ __forceinline__ unsigned short f2bf(float f) {  // RNE
  union { float f; unsigned u; } v; v.f = f;
  unsigned r = v.u + 0x7fffu + ((v.u >> 16) & 1u);
  return (unsigned short)(r >> 16);
}
__device__ __forceinline__ float bf2f(unsigned short s) {
  union { unsigned u; float f; } v; v.u = ((unsigned)s) << 16;
  return v.f;
}
__device__ __forceinline__ float bflo(unsigned u) { return __uint_as_float(u << 16); }
__device__ __forceinline__ float bfhi(unsigned u) { return __uint_as_float(u & 0xffff0000u); }
__device__ __forceinline__ unsigned pack2(float lo, float hi) {
  return (unsigned)f2bf(lo) | ((unsigned)f2bf(hi) << 16);
}
__device__ __forceinline__ void st_bf4(unsigned short* p, float4 v) {
  uint2 o; o.x = pack2(v.x, v.y); o.y = pack2(v.z, v.w);
  *(uint2*)p = o;
}

// ---------------- fp8 e4m3fn helpers ----------------
#if __has_builtin(__builtin_amdgcn_cvt_pk_f32_fp8) && __has_builtin(__builtin_amdgcn_cvt_pk_fp8_f32)
#define HAVE_FP8_CVT 1
#endif

#ifndef HAVE_FP8_CVT
__device__ __forceinline__ float fp8_dec1(unsigned b) {
  unsigned s = (b >> 7) & 1u, E = (b >> 3) & 15u, m = b & 7u;
  float v;
  if (E) {
    union { unsigned u; float f; } t;
    t.u = (s << 31) | ((E + 120u) << 23) | (m << 20);
    v = t.f;
  } else {
    v = (s ? -1.f : 1.f) * (float)m * 0.001953125f;
  }
  return v;
}
#endif

template <bool HI>
__device__ __forceinline__ fv2 fp8x2(unsigned u) {
#ifdef HAVE_FP8_CVT
  return __builtin_amdgcn_cvt_pk_f32_fp8((int)u, HI);
#else
  unsigned p = HI ? (u >> 16) : u;
  fv2 r; r.x = fp8_dec1(p & 0xffu); r.y = fp8_dec1((p >> 8) & 0xffu);
  return r;
#endif
}

__device__ __forceinline__ unsigned char f32_to_fp8(float f) {
#ifdef HAVE_FP8_CVT
  return (unsigned char)(__builtin_amdgcn_cvt_pk_fp8_f32(f, f, 0, false) & 0xff);
#else
  union { float f; unsigned u; } t; t.f = f;
  unsigned s = t.u >> 31;
  float a = fabsf(f);
  if (a > 448.f) a = 448.f;
  t.f = a;
  int e = (int)((t.u >> 23) & 0xff) - 127;
  unsigned char r;
  if (a == 0.f) {
    r = 0;
  } else if (e >= -6) {
    unsigned m = t.u & 0x7fffffu;
    unsigned keep = m >> 20, rest = m & 0xfffffu;
    keep += (rest > 0x80000u) || (rest == 0x80000u && (keep & 1u));
    int E = e + 7;
    if (keep == 8u) { keep = 0u; E += 1; }
    if (E >= 16) { E = 15; keep = 6u; }
    r = (unsigned char)((E << 3) | keep);
  } else {
    int mi = (int)(a * 512.f + 0.5f);
    r = (mi > 7) ? (unsigned char)(1u << 3) : (unsigned char)mi;
  }
  return (unsigned char)(r | (s << 7));
#endif
}

// ---------------- k_ws: W -> bf16 transposed ----------------
__global__ void k_ws(const float* __restrict__ W_conv,
                     const float* __restrict__ W_res,
                     unsigned short* __restrict__ whiT) {
  int base = blockIdx.x * 1024;
#pragma unroll
  for (int j = 0; j < 4; ++j) {
    int idx = base + j * 256 + threadIdx.x;
    if (idx < 5 * H * H) {
      int m = idx >> 14, rr = idx & 16383;
      int k = rr >> 7, n = rr & 127;
      const float* src = (m < 4) ? (W_conv + m * H * H) : W_res;
      whiT[m * H * H + n * H + k] = f2bf(src[k * H + n]);
    }
  }
}

// mm from LDS tile: 64 rows x 128 cols, wave = 32r x 64c (B frags hoisted)
__device__ __forceinline__ void mm_lds_fp8(const unsigned short* sA,
                                           const unsigned short* __restrict__ WT,
                                           int n0, int t,
                                           unsigned char* __restrict__ htOut) {
  int wave = t >> 6, lane = t & 63;
  int wr = wave >> 1, wc = wave & 1;
  int m = lane & 15, quad = (lane >> 4) & 3;
  short8 bh[4][4];
#pragma unroll
  for (int q = 0; q < 4; ++q)
#pragma unroll
    for (int ct = 0; ct < 4; ++ct) {
      int n = wc * 64 + ct * 16 + m;
      bh[q][ct] = *(const short8*)(WT + n * H + q * 32 + quad * 8);
    }
  f32x4 acc[2][4];
#pragma unroll
  for (int i = 0; i < 2; ++i)
#pragma unroll
    for (int j = 0; j < 4; ++j) acc[i][j] = (f32x4){0.f, 0.f, 0.f, 0.f};
#pragma unroll
  for (int q = 0; q < 4; ++q) {
    short8 ah[2];
#pragma unroll
    for (int rt = 0; rt < 2; ++rt)
      ah[rt] = *(const short8*)(sA + (wr * 32 + rt * 16 + m) * 136 + q * 32 + quad * 8);
#pragma unroll
    for (int rt = 0; rt < 2; ++rt)
#pragma unroll
      for (int ct = 0; ct < 4; ++ct)
        acc[rt][ct] = __builtin_amdgcn_mfma_f32_16x16x32_bf16(ah[rt], bh[q][ct], acc[rt][ct], 0, 0, 0);
  }
#pragma unroll
  for (int rt = 0; rt < 2; ++rt)
#pragma unroll
    for (int ct = 0; ct < 4; ++ct) {
      int col = wc * 64 + ct * 16 + m;
#pragma unroll
      for (int rr = 0; rr < 4; ++rr) {
        int gn = n0 + wr * 32 + rt * 16 + quad * 4 + rr;
        if (gn < N_NODES) htOut[(size_t)gn * H + col] = f32_to_fp8(acc[rt][ct][rr]);
      }
    }
}

// ---------------- k_pre3: hist | (embed 64-node tile -> LDS -> mm W0), 1:2 ----------------
__global__ __launch_bounds__(256) void k_pre3(
    const int* __restrict__ ei, int* __restrict__ deg,
    unsigned char* __restrict__ ranks,
    const float* __restrict__ x, const float* __restrict__ W_emb,
    const float* __restrict__ b_emb, unsigned short* __restrict__ h,
    const unsigned short* __restrict__ W0T, unsigned char* __restrict__ ht8) {
  __shared__ __align__(16) char smem[25600];
  int t = threadIdx.x;
  int id = blockIdx.x;
  int q3 = id / 3, r3 = id - q3 * 3;
  if (r3 == 0) {
    int i = q3 * 256 + t;
    if (i < NEDGES / 8) {
      int4 a = *(const int4*)(ei + NEDGES + 8 * i);
      int4 b = *(const int4*)(ei + NEDGES + 8 * i + 4);
      union { unsigned char c[8]; uint2 u; } rr;
      rr.c[0] = (unsigned char)atomicAdd(&deg[a.x], 1);
      rr.c[1] = (unsigned char)atomicAdd(&deg[a.y], 1);
      rr.c[2] = (unsigned char)atomicAdd(&deg[a.z], 1);
      rr.c[3] = (unsigned char)atomicAdd(&deg[a.w], 1);
      rr.c[4] = (unsigned char)atomicAdd(&deg[b.x], 1);
      rr.c[5] = (unsigned char)atomicAdd(&deg[b.y], 1);
      rr.c[6] = (unsigned char)atomicAdd(&deg[b.z], 1);
      rr.c[7] = (unsigned char)atomicAdd(&deg[b.w], 1);
      ((uint2*)ranks)[i] = rr.u;
    }
  } else {
    int j = q3 * 2 + (r3 - 1);
    int n0 = j * 64;
    float* sW = (float*)smem;
    float* sX = sW + 4096;
    unsigned short* sH = (unsigned short*)smem;
#pragma unroll
    for (int p = 0; p < 4; ++p)
      ((float4*)sW)[t + p * 256] = ((const float4*)W_emb)[t + p * 256];
#pragma unroll
    for (int p = 0; p < 2; ++p) {
      int fi = t * 2 + p;
      int row = fi >> 3, k4 = (fi & 7) * 4;
      int gn = n0 + row; if (gn >= N_NODES) gn = N_NODES - 1;
      *(float4*)(sX + row * 36 + k4) = *(const float4*)(x + (size_t)gn * F_IN + k4);
    }
    __syncthreads();
    // conflict-free sW reads: col0 = (t&3)*4 -> banks {0,4,8,12}(+16i)
    int nr = t >> 2, col0 = (t & 3) * 4;
    float4 acc[8];
#pragma unroll
    for (int i = 0; i < 8; ++i) acc[i] = make_float4(0.f, 0.f, 0.f, 0.f);
#pragma unroll 4
    for (int k = 0; k < F_IN; ++k) {
      float xv = sX[nr * 36 + k];
      const float* wp = sW + k * H + col0;
#pragma unroll
      for (int i = 0; i < 8; ++i) fma4(acc[i], xv, *(const float4*)(wp + i * 16));
    }
#pragma unroll
    for (int i = 0; i < 8; ++i) {
      float4 bv = *(const float4*)(b_emb + col0 + i * 16);
      acc[i].x += bv.x; acc[i].y += bv.y; acc[i].z += bv.z; acc[i].w += bv.w;
    }
    __syncthreads();  // done reading sW/sX; reuse as sH
    int node = n0 + nr;
    unsigned short* hr = h + (size_t)node * H + col0;
#pragma unroll
    for (int i = 0; i < 8; ++i) {
      st_bf4(sH + nr * 136 + col0 + i * 16, acc[i]);
      if (node < N_NODES) st_bf4(hr + i * 16, acc[i]);
    }
    __syncthreads();
    mm_lds_fp8(sH, W0T, n0, t, ht8);
  }
}

// ---------------- scans ----------------
__global__ void k_scan_a(const int* __restrict__ deg, int* __restrict__ offs,
                         int* __restrict__ parts, float* __restrict__ dinv) {
  __shared__ int s[256];
  int i = blockIdx.x * 256 + threadIdx.x;
  int d = (i < N_NODES) ? deg[i] : 0;
  s[threadIdx.x] = d;
  __syncthreads();
#pragma unroll
  for (int off = 1; off < 256; off <<= 1) {
    int v = (threadIdx.x >= off) ? s[threadIdx.x - off] : 0;
    __syncthreads();
    s[threadIdx.x] += v;
    __syncthreads();
  }
  if (i < N_NODES) {
    offs[i] = s[threadIdx.x] - d;   // block-local exclusive
    dinv[i] = rsqrtf((float)(d + 1));
  }
  if (threadIdx.x == 255) parts[blockIdx.x] = s[255];
}

__global__ void k_scan_b(int* __restrict__ parts, int nparts) {
  __shared__ int s[512];
  int t = threadIdx.x;
  int d = (t < nparts) ? parts[t] : 0;
  s[t] = d;
  __syncthreads();
#pragma unroll
  for (int off = 1; off < 512; off <<= 1) {
    int v = (t >= off) ? s[t - off] : 0;
    __syncthreads();
    s[t] += v;
    __syncthreads();
  }
  if (t < nparts) parts[t] = s[t] - d;
}

// ---------------- k_fill ----------------
__global__ __launch_bounds__(256) void k_fill(
    const int* __restrict__ ei, const unsigned char* __restrict__ ranks,
    const int* __restrict__ offs, const int* __restrict__ parts,
    const float* __restrict__ dinv, unsigned* __restrict__ csr) {
  int i = blockIdx.x * 256 + threadIdx.x;
  if (i < NEDGES / 4) {
    int4 s4 = *(const int4*)(ei + 4 * i);
    int4 d4 = *(const int4*)(ei + NEDGES + 4 * i);
    uchar4 r4 = ((const uchar4*)ranks)[i];
    int p0 = offs[d4.x] + parts[d4.x >> 8] + r4.x;
    int p1 = offs[d4.y] + parts[d4.y >> 8] + r4.y;
    int p2 = offs[d4.z] + parts[d4.z >> 8] + r4.z;
    int p3 = offs[d4.w] + parts[d4.w >> 8] + r4.w;
    csr[p0] = ((unsigned)s4.x << 15) | (unsigned)(dinv[s4.x] * 32767.f + 0.5f);
    csr[p1] = ((unsigned)s4.y << 15) | (unsigned)(dinv[s4.y] * 32767.f + 0.5f);
    csr[p2] = ((unsigned)s4.z << 15) | (unsigned)(dinv[s4.z] * 32767.f + 0.5f);
    csr[p3] = ((unsigned)s4.w << 15) | (unsigned)(dinv[s4.w] * 32767.f + 0.5f);
  }
}

// ---------------- mm core for layers 1-3 (global A) ----------------
struct MMAcc { f32x4 a[2][2]; };

__device__ __forceinline__ MMAcc mm_core(const unsigned short* __restrict__ A,
                                         const unsigned short* __restrict__ WhiT,
                                         int n0, int c0, int t,
                                         unsigned short* sA) {
  int wave = t >> 6, lane = t & 63;
  int wr = wave >> 1, wc = wave & 1;
  int m = lane & 15, quad = (lane >> 4) & 3;
  short8 bh[4][2];
#pragma unroll
  for (int q = 0; q < 4; ++q)
#pragma unroll
    for (int ct = 0; ct < 2; ++ct) {
      int n = c0 + wc * 32 + ct * 16 + m;
      bh[q][ct] = *(const short8*)(WhiT + n * H + q * 32 + quad * 8);
    }
#pragma unroll
  for (int p = 0; p < 4; ++p) {
    int fi = t + p * 256;
    int row = fi >> 4, c8 = (fi & 15) * 8;
    int gn = n0 + row; if (gn >= N_NODES) gn = N_NODES - 1;
    *(uint4*)(sA + row * 136 + c8) = *(const uint4*)(A + (size_t)gn * H + c8);
  }
  __syncthreads();
  MMAcc r;
#pragma unroll
  for (int i = 0; i < 2; ++i)
#pragma unroll
    for (int j = 0; j < 2; ++j) r.a[i][j] = (f32x4){0.f, 0.f, 0.f, 0.f};
#pragma unroll
  for (int q = 0; q < 4; ++q) {
    short8 ah[2];
#pragma unroll
    for (int rt = 0; rt < 2; ++rt)
      ah[rt] = *(const short8*)(sA + (wr * 32 + rt * 16 + m) * 136 + q * 32 + quad * 8);
#pragma unroll
    for (int rt = 0; rt < 2; ++rt)
#pragma unroll
      for (int ct = 0; ct < 2; ++ct)
        r.a[rt][ct] = __builtin_amdgcn_mfma_f32_16x16x32_bf16(ah[rt], bh[q][ct], r.a[rt][ct], 0, 0, 0);
  }
  return r;
}

__device__ __forceinline__ void mm_store_fp8(const MMAcc& r, unsigned char* ht8,
                                             int n0, int c0, int t) {
  int wave = t >> 6, lane = t & 63;
  int wr = wave >> 1, wc = wave & 1;
  int m = lane & 15, quad = (lane >> 4) & 3;
#pragma unroll
  for (int rt = 0; rt < 2; ++rt)
#pragma unroll
    for (int ct = 0; ct < 2; ++ct) {
      int col = c0 + wc * 32 + ct * 16 + m;
#pragma unroll
      for (int rr = 0; rr < 4; ++rr) {
        int gn = n0 + wr * 32 + rt * 16 + quad * 4 + rr;
        if (gn < N_NODES) ht8[(size_t)gn * H + col] = f32_to_fp8(r.a[rt][ct][rr]);
      }
    }
}

__global__ __launch_bounds__(256) void k_mm(const unsigned short* __restrict__ A,
                                            const unsigned short* __restrict__ WhiT,
                                            unsigned char* __restrict__ ht8) {
  __shared__ __align__(16) unsigned short sA[64 * 136];
  int j = blockIdx.x;
  int n0 = (j >> 1) * 64, c0 = (j & 1) * 64;
  MMAcc r = mm_core(A, WhiT, n0, c0, threadIdx.x, sA);
  mm_store_fp8(r, ht8, n0, c0, threadIdx.x);
}

// layer-2 dual GEMM
__global__ __launch_bounds__(256) void k_mmd(const unsigned short* __restrict__ A,
    const unsigned short* __restrict__ WcT, const unsigned short* __restrict__ WrT,
    const float* __restrict__ bias,
    unsigned char* __restrict__ ht8, unsigned short* __restrict__ resb) {
  __shared__ __align__(16) unsigned short sA[64 * 136];
  int t = threadIdx.x;
  int j = blockIdx.x;
  int n0 = (j >> 1) * 64, c0 = (j & 1) * 64;
  int wave = t >> 6, lane = t & 63;
  int wr = wave >> 1, wc = wave & 1;
  int m = lane & 15, quad = (lane >> 4) & 3;
  short8 bhc[4][2], bhr[4][2];
#pragma unroll
  for (int q = 0; q < 4; ++q)
#pragma unroll
    for (int ct = 0; ct < 2; ++ct) {
      int n = c0 + wc * 32 + ct * 16 + m;
      bhc[q][ct] = *(const short8*)(WcT + n * H + q * 32 + quad * 8);
      bhr[q][ct] = *(const short8*)(WrT + n * H + q * 32 + quad * 8);
    }
#pragma unroll
  for (int p = 0; p < 4; ++p) {
    int fi = t + p * 256;
    int row = fi >> 4, c8 = (fi & 15) * 8;
    int gn = n0 + row; if (gn >= N_NODES) gn = N_NODES - 1;
    *(uint4*)(sA + row * 136 + c8) = *(const uint4*)(A + (size_t)gn * H + c8);
  }
  __syncthreads();
  f32x4 accC[2][2], accR[2][2];
#pragma unroll
  for (int i = 0; i < 2; ++i)
#pragma unroll
    for (int jj = 0; jj < 2; ++jj) {
      accC[i][jj] = (f32x4){0.f, 0.f, 0.f, 0.f};
      accR[i][jj] = (f32x4){0.f, 0.f, 0.f, 0.f};
    }
#pragma unroll
  for (int q = 0; q < 4; ++q) {
    short8 ah[2];
#pragma unroll
    for (int rt = 0; rt < 2; ++rt)
      ah[rt] = *(const short8*)(sA + (wr * 32 + rt * 16 + m) * 136 + q * 32 + quad * 8);
#pragma unroll
    for (int rt = 0; rt < 2; ++rt)
#pragma unroll
      for (int ct = 0; ct < 2; ++ct) {
        accC[rt][ct] = __builtin_amdgcn_mfma_f32_16x16x32_bf16(ah[rt], bhc[q][ct], accC[rt][ct], 0, 0, 0);
        accR[rt][ct] = __builtin_amdgcn_mfma_f32_16x16x32_bf16(ah[rt], bhr[q][ct], accR[rt][ct], 0, 0, 0);
      }
  }
#pragma unroll
  for (int rt = 0; rt < 2; ++rt)
#pragma unroll
    for (int ct = 0; ct < 2; ++ct) {
      int col = c0 + wc * 32 + ct * 16 + m;
      float bv = bias[col];
#pragma unroll
      for (int rr = 0; rr < 4; ++rr) {
        int gn = n0 + wr * 32 + rt * 16 + quad * 4 + rr;
        if (gn < N_NODES) {
          ht8[(size_t)gn * H + col]  = f32_to_fp8(accC[rt][ct][rr]);
          resb[(size_t)gn * H + col] = f2bf(accR[rt][ct][rr] + bv);
        }
      }
    }
}

// ---------------- aggregate(fp8 ht) + bias + LN + relu + residual(bf16) ----------------
// r14 layout (4 groups x 16 lanes, uint2 gathers) -- r15's 8x16B layout was
// VALU/TA-bound (90 us, VALUBusy 74%). Deepened to 32-edge rounds: 8 uint2
// loads in flight per lane.
__global__ __launch_bounds__(256) void k_agg(
    const unsigned char* __restrict__ ht8, const unsigned short* __restrict__ res,
    const float* __restrict__ dinv, const int* __restrict__ offs,
    const int* __restrict__ parts, const int* __restrict__ deg,
    const unsigned* __restrict__ csr,
    const float* __restrict__ bias, const float* __restrict__ lng,
    const float* __restrict__ lnb, unsigned short* __restrict__ hout) {
  int wid = threadIdx.x >> 6, lane = threadIdx.x & 63;
  int node = blockIdx.x * 4 + wid;
  if (node >= N_NODES) return;
  int grp = lane >> 4, fl = lane & 15;
  int start = offs[node] + parts[node >> 8], cnt = deg[node];
  float di = dinv[node];
  const unsigned char* hb = ht8 + fl * 8;
  float acc[8];
  {
    uint2 u = *(const uint2*)(hb + (size_t)node * 128);
    float sw = (grp == 0) ? di * di : 0.f;
    fv2 a = fp8x2<false>(u.x), b = fp8x2<true>(u.x);
    fv2 c = fp8x2<false>(u.y), d2 = fp8x2<true>(u.y);
    acc[0] = sw * a.x; acc[1] = sw * a.y;
    acc[2] = sw * b.x; acc[3] = sw * b.y;
    acc[4] = sw * c.x; acc[5] = sw * c.y;
    acc[6] = sw * d2.x; acc[7] = sw * d2.y;
  }
  float ddq = di * (1.f / 32767.f);
  for (int b0 = 0; b0 < cnt; b0 += 64) {
    int mm_ = min(64, cnt - b0);
    int s = 0; float w = 0.f;
    if (lane < mm_) {
      unsigned ev = csr[start + b0 + lane];
      s = (int)(ev >> 15);
      w = (float)(ev & 32767u) * ddq;
    }
    for (int e0 = 0; e0 < mm_; e0 += 32) {
      uint2 uu[8]; float ww[8];
#pragma unroll
      for (int jj = 0; jj < 8; ++jj) {
        int idx = e0 + jj * 4 + grp;   // <= 32+28+3 = 63 always
        int ss = __shfl(s, idx, 64);
        ww[jj] = __shfl(w, idx, 64);
        uu[jj] = *(const uint2*)(hb + (size_t)ss * 128);
      }
#pragma unroll
      for (int jj = 0; jj < 8; ++jj) {
        float we = ww[jj];
        fv2 a = fp8x2<false>(uu[jj].x), b = fp8x2<true>(uu[jj].x);
        fv2 c = fp8x2<false>(uu[jj].y), d2 = fp8x2<true>(uu[jj].y);
        acc[0] = fmaf(we, a.x, acc[0]);
        acc[1] = fmaf(we, a.y, acc[1]);
        acc[2] = fmaf(we, b.x, acc[2]);
        acc[3] = fmaf(we, b.y, acc[3]);
        acc[4] = fmaf(we, c.x, acc[4]);
        acc[5] = fmaf(we, c.y, acc[5]);
        acc[6] = fmaf(we, d2.x, acc[6]);
        acc[7] = fmaf(we, d2.y, acc[7]);
      }
    }
  }
#pragma unroll
  for (int j = 0; j < 8; ++j) {
    acc[j] += __shfl_xor(acc[j], 16, 64);
    acc[j] += __shfl_xor(acc[j], 32, 64);
  }
  float4 b0v = *(const float4*)(bias + fl * 8);
  float4 b1v = *(const float4*)(bias + fl * 8 + 4);
  acc[0] += b0v.x; acc[1] += b0v.y; acc[2] += b0v.z; acc[3] += b0v.w;
  acc[4] += b1v.x; acc[5] += b1v.y; acc[6] += b1v.z; acc[7] += b1v.w;
  float sl = ((acc[0] + acc[1]) + (acc[2] + acc[3])) +
             ((acc[4] + acc[5]) + (acc[6] + acc[7]));
#pragma unroll
  for (int mk = 1; mk <= 8; mk <<= 1) sl += __shfl_xor(sl, mk, 64);
  float mu = sl * (1.f / 128.f);
  float d[8];
  float vl = 0.f;
#pragma unroll
  for (int j = 0; j < 8; ++j) { d[j] = acc[j] - mu; vl = fmaf(d[j], d[j], vl); }
#pragma unroll
  for (int mk = 1; mk <= 8; mk <<= 1) vl += __shfl_xor(vl, mk, 64);
  float rs = rsqrtf(vl * (1.f / 128.f) + EPS);
  if (grp == 0) {
    float4 g0 = *(const float4*)(lng + fl * 8);
    float4 g1 = *(const float4*)(lng + fl * 8 + 4);
    float4 be0 = *(const float4*)(lnb + fl * 8);
    float4 be1 = *(const float4*)(lnb + fl * 8 + 4);
    uint4 rv = *(const uint4*)(res + (size_t)node * 128 + fl * 8);
    float o0 = fmaxf(fmaf(d[0] * rs, g0.x, be0.x), 0.f) + bflo(rv.x);
    float o1 = fmaxf(fmaf(d[1] * rs, g0.y, be0.y), 0.f) + bfhi(rv.x);
    float o2 = fmaxf(fmaf(d[2] * rs, g0.z, be0.z), 0.f) + bflo(rv.y);
    float o3 = fmaxf(fmaf(d[3] * rs, g0.w, be0.w), 0.f) + bfhi(rv.y);
    float o4 = fmaxf(fmaf(d[4] * rs, g1.x, be1.x), 0.f) + bflo(rv.z);
    float o5 = fmaxf(fmaf(d[5] * rs, g1.y, be1.y), 0.f) + bfhi(rv.z);
    float o6 = fmaxf(fmaf(d[6] * rs, g1.z, be1.z), 0.f) + bflo(rv.w);
    float o7 = fmaxf(fmaf(d[7] * rs, g1.w, be1.w), 0.f) + bfhi(rv.w);
    uint4 ov;
    ov.x = pack2(o0, o1); ov.y = pack2(o2, o3);
    ov.z = pack2(o4, o5); ov.w = pack2(o6, o7);
    *(uint4*)(hout + (size_t)node * 128 + fl * 8) = ov;
  }
}

// ---------------- mean pool (bf16 h, vectorized uint4 loads) ----------------
__global__ __launch_bounds__(256) void k_pool(const unsigned short* __restrict__ h,
                                              float* __restrict__ pool) {
  __shared__ float colsum[128];
  int t = threadIdx.x;
  if (t < 128) colsum[t] = 0.f;
  __syncthreads();
  int lr = t >> 4, seg = t & 15;   // 16 rows/pass, 16 x uint4 per row
  float acc[8] = {0.f, 0.f, 0.f, 0.f, 0.f, 0.f, 0.f, 0.f};
  for (int n = blockIdx.x * 16 + lr; n < N_NODES; n += gridDim.x * 16) {
    uint4 u = *(const uint4*)(h + (size_t)n * H + seg * 8);
    acc[0] += bflo(u.x); acc[1] += bfhi(u.x);
    acc[2] += bflo(u.y); acc[3] += bfhi(u.y);
    acc[4] += bflo(u.z); acc[5] += bfhi(u.z);
    acc[6] += bflo(u.w); acc[7] += bfhi(u.w);
  }
#pragma unroll
  for (int j = 0; j < 8; ++j) atomicAdd(&colsum[seg * 8 + j], acc[j]);
  __syncthreads();
  if (t < 128) atomicAdd(&pool[t], colsum[t]);
}

// ---------------- head ----------------
__global__ void k_head(const float* __restrict__ pool, const float* __restrict__ Wfc1,
                       const float* __restrict__ bfc1, const float* __restrict__ g,
                       const float* __restrict__ bb, const float* __restrict__ Wfc2,
                       const float* __restrict__ bfc2, float* __restrict__ out) {
  __shared__ float sm[128], s1[128], stats[2];
  int t = threadIdx.x;
  if (t < 128) sm[t] = pool[t] * (1.f / (float)N_NODES);
  __syncthreads();
  if (t < 128) {
    float a = bfc1[t];
    for (int k = 0; k < 128; ++k) a = fmaf(sm[k], Wfc1[k * 128 + t], a);
    s1[t] = a;
  }
  __syncthreads();
  if (t == 0) {
    float mu = 0.f;
    for (int k = 0; k < 128; ++k) mu += s1[k];
    mu *= (1.f / 128.f);
    float var = 0.f;
    for (int k = 0; k < 128; ++k) { float d = s1[k] - mu; var += d * d; }
    var *= (1.f / 128.f);
    stats[0] = mu; stats[1] = rsqrtf(var + EPS);
  }
  __syncthreads();
  if (t < 128) s1[t] = fmaxf((s1[t] - stats[0]) * stats[1] * g[t] + bb[t], 0.f);
  __syncthreads();
  if (t < OUT_F) {
    float a = bfc2[t];
    for (int k = 0; k < 128; ++k) a = fmaf(s1[k], Wfc2[k * OUT_F + t], a);
    out[t] = a;
  }
}

extern "C" void kernel_launch(void* const* d_in, const int* in_sizes, int n_in,
                              void* d_out, int out_size, void* d_ws, size_t ws_size,
                              hipStream_t stream) {
  const float* x      = (const float*)d_in[0];
  const int*   ei     = (const int*)d_in[1];
  const float* W_emb  = (const float*)d_in[2];
  const float* b_emb  = (const float*)d_in[3];
  const float* W_conv = (const float*)d_in[4];
  const float* b_conv = (const float*)d_in[5];
  const float* ln_g   = (const float*)d_in[6];
  const float* ln_b   = (const float*)d_in[7];
  const float* W_res  = (const float*)d_in[8];
  const float* b_res  = (const float*)d_in[9];
  const float* W_fc1  = (const float*)d_in[10];
  const float* b_fc1  = (const float*)d_in[11];
  const float* fcn_g  = (const float*)d_in[12];
  const float* fcn_b  = (const float*)d_in[13];
  const float* W_fc2  = (const float*)d_in[14];
  const float* b_fc2  = (const float*)d_in[15];
  float* out = (float*)d_out;

  char* p = (char*)d_ws;
  auto take = [&](size_t bytes) {
    char* r = p; p += (bytes + 255) & ~(size_t)255; return r;
  };
  unsigned short* bufA = (unsigned short*)take((size_t)N_NODES * H * 2);
  unsigned short* bufB = (unsigned short*)take((size_t)N_NODES * H * 2);
  unsigned short* bufC = (unsigned short*)take((size_t)N_NODES * H * 2);
  unsigned char*  ht8  = (unsigned char*)take((size_t)N_NODES * H);
  unsigned short* whiT = (unsigned short*)take((size_t)5 * H * H * 2);
  int*   deg  = (int*)take(N_NODES * 4);
  int*   offs = (int*)take(N_NODES * 4);
  int*   parts= (int*)take(512 * 4);
  float* dinv = (float*)take(N_NODES * 4);
  unsigned char* ranks = (unsigned char*)take(NEDGES);
  unsigned* csr = (unsigned*)take((size_t)NEDGES * 4);
  float* pool = (float*)take(128 * 4);

  (void)hipMemsetAsync(deg, 0, N_NODES * 4, stream);
  (void)hipMemsetAsync(pool, 0, 128 * 4, stream);

  k_ws<<<WS_BLKS, 256, 0, stream>>>(W_conv, W_res, whiT);
  k_pre3<<<PRE3_BLKS, 256, 0, stream>>>(ei, deg, ranks, x, W_emb, b_emb, bufA,
                                        whiT + 0 * H * H, ht8);
  k_scan_a<<<NPARTS, 256, 0, stream>>>(deg, offs, parts, dinv);
  k_scan_b<<<1, 512, 0, stream>>>(parts, NPARTS);
  k_fill<<<FILL_BLKS, 256, 0, stream>>>(ei, ranks, offs, parts, dinv, csr);

  int aggg = (N_NODES + 3) / 4;
  // L0: res=h0=A -> h1=C
  k_agg<<<aggg, 256, 0, stream>>>(ht8, bufA, dinv, offs, parts, deg, csr,
                                  b_conv + 0 * H, ln_g + 0 * H, ln_b + 0 * H, bufC);
  // L1: h1=C -> ht8 -> h2=A (res=C)
  k_mm<<<MM_BLKS, 256, 0, stream>>>(bufC, whiT + 1 * H * H, ht8);
  k_agg<<<aggg, 256, 0, stream>>>(ht8, bufC, dinv, offs, parts, deg, csr,
                                  b_conv + 1 * H, ln_g + 1 * H, ln_b + 1 * H, bufA);
  // L2: h2=A; dual: ht8=A@W2, B=bf16(A@Wres+bres); agg -> h3=C (res=B)
  k_mmd<<<MM_BLKS, 256, 0, stream>>>(bufA, whiT + 2 * H * H, whiT + 4 * H * H,
                                     b_res, ht8, bufB);
  k_agg<<<aggg, 256, 0, stream>>>(ht8, bufB, dinv, offs, parts, deg, csr,
                                  b_conv + 2 * H, ln_g + 2 * H, ln_b + 2 * H, bufC);
  // L3: h3=C -> ht8 -> h4=A (res=C)
  k_mm<<<MM_BLKS, 256, 0, stream>>>(bufC, whiT + 3 * H * H, ht8);
  k_agg<<<aggg, 256, 0, stream>>>(ht8, bufC, dinv, offs, parts, deg, csr,
                                  b_conv + 3 * H, ln_g + 3 * H, ln_b + 3 * H, bufA);

  k_pool<<<256, 256, 0, stream>>>(bufA, pool);
  k_head<<<1, 256, 0, stream>>>(pool, W_fc1, b_fc1, fcn_g, fcn_b,
                                W_fc2, b_fc2, out);
}